// Round 5
// baseline (51.269 us; speedup 1.0000x reference)
//
#include <hip/hip_runtime.h>
#include <stdint.h>

// Soft decision-tree ensemble, collapsed to:
//   out[b,c] = sum_t ( A'[t,c] + sum_{k<4} d[b,t,k]*B'[t,k,c] ) / (4 + d[b,t,3] + 1e-8)
//   d[b,t,k] = sigmoid( X[b,:] . W[t,k,:] + bias[t,k] ),  nodes 0..3 only.
// GEMM 65536x512 @ 512x256, memory-bound on X (134 MB fp32 read once).
// R5: latency-slack fix. BK=16, 32 k-steps, mfma 16x16x16_f16 (low VGPR).
//     X ring-3 regs (issue kt+3), W gll ring-3 (issue kt+2); vmcnt(2) certifies
//     the two OLDEST ops {W(kt), X(kt+1)} -> every load gets 2 full periods of
//     latency slack; >=64KB/CU in flight at all times. 2 blocks/CU.

#define KDIM 512
#define PPT 3607

typedef _Float16 f16x4 __attribute__((ext_vector_type(4)));
typedef float f32x4 __attribute__((ext_vector_type(4)));

// ws layout (bytes):
//   [0, 262144)       Wh   : _Float16 [256 cols][512 k]   (col = t*4 + node)
//   [262144, 263168)  biasN: float[256]
//   [263168, 265728)  AB   : float[64][10]

__global__ __launch_bounds__(128) void prep_kernel(const float* __restrict__ p,
                                                   const float* __restrict__ tw,
                                                   _Float16* __restrict__ Wh,
                                                   float* __restrict__ biasN,
                                                   float* __restrict__ AB) {
    const int c = blockIdx.x;          // 0..255
    const int t = c >> 2, i = c & 3;
    const float* wsrc = p + t * PPT + i * KDIM;
    for (int k = threadIdx.x; k < KDIM; k += 128)
        Wh[c * KDIM + k] = (_Float16)wsrc[k];
    if (threadIdx.x == 0)
        biasN[c] = p[t * PPT + 7 * KDIM + i];
    if (threadIdx.x == 64 && c < 64) {
        const int tt = c;
        const float* lg = p + tt * PPT + 7 * 513;   // leaf logits, 8 x 2
        const float w = tw[tt];
        float ld[8][2];
#pragma unroll
        for (int j = 0; j < 8; ++j) {
            float a = lg[2 * j], b = lg[2 * j + 1];
            float m = fmaxf(a, b);
            float e0 = expf(a - m), e1 = expf(b - m);
            float s = e0 + e1;
            ld[j][0] = e0 / s; ld[j][1] = e1 / s;
        }
        float* o = AB + tt * 10;
#pragma unroll
        for (int cc = 0; cc < 2; ++cc) {
            o[0 + cc] = w * (ld[0][cc] + ld[2][cc] + ld[4][cc] + ld[6][cc]);
            o[2 + cc] = w * (ld[1][cc] - ld[2][cc]);
            o[4 + cc] = w * (ld[3][cc] - ld[4][cc]);
            o[6 + cc] = w * (ld[5][cc] - ld[6][cc]);
            o[8 + cc] = w * (ld[7][cc]);
        }
    }
}

// LDS (73728 B, 2 blocks/CU):
//   xbuf[2]: f16 [128 rows][16 k], 40B/row pad, at b*5120   (0-conflict b64 reads)
//   wbuf[3]: f16 [256 cols][16 k], 32B/col linear (gll), at 10240 + m*8192
//            16B-granule swizzle: LDS granule (c,g) holds global quad-pair g^((c>>2)&1)
//   epilogue overlay (loop-dead): E f32 [64][260] at 0; P f32 [64][18] at 66560;
//   AB f32[640] at 71168.
#define XB_STRIDE 5120
#define WB0 10240
#define WB_STRIDE 8192
#define EPI_S 260
#define P_OFF 66560
#define P_S 18
#define AB_OFF 71168
#define LDS_BYTES 73728

__device__ __forceinline__ void gll16(const void* g, void* l) {
    __builtin_amdgcn_global_load_lds((const __attribute__((address_space(1))) uint32_t*)g,
                                     (__attribute__((address_space(3))) uint32_t*)l, 16, 0, 0);
}

__device__ __forceinline__ f16x4 cvt4(float4 a) {
    f16x4 h;
    h[0] = (_Float16)a.x; h[1] = (_Float16)a.y;
    h[2] = (_Float16)a.z; h[3] = (_Float16)a.w;
    return h;
}

__global__ __launch_bounds__(512, 4) void main_kernel(const float* __restrict__ X,
                                                      const _Float16* __restrict__ Wh,
                                                      const float* __restrict__ biasN,
                                                      const float* __restrict__ ABg,
                                                      float* __restrict__ out) {
    extern __shared__ char smem[];
    const int tid = threadIdx.x;
    const int lane = tid & 63;
    const int w = tid >> 6;          // wave 0..7
    const int wm = w >> 2;           // 0..1 : 64-row half
    const int wn = w & 3;            // 0..3 : 64-col quarter
    const int r15 = lane & 15;
    const int hi = lane >> 4;        // 0..3
    const int gr0 = blockIdx.x * 128;

    // AB coeffs -> LDS (own region); then clean vmcnt slate for counted waits
    {
        float* abl = (float*)(smem + AB_OFF);
        for (int i = tid; i < 640; i += 512) abl[i] = ABg[i];
    }
    asm volatile("s_waitcnt vmcnt(0)" ::: "memory");

    // X staging: thread owns row=tid>>2, f32-quad g=tid&3 (16B/step)
    const int xrow = tid >> 2, xg = tid & 3;
    const float* Xp = X + (size_t)(gr0 + xrow) * KDIM + xg * 4;
    const int xw = xrow * 40 + xg * 8;                  // byte offset in xbuf

    // W staging: thread owns col=tid>>1, 16B granule g=tid&1 (pre-swizzled source)
    const int wc = tid >> 1, wgr = tid & 1;
    const _Float16* Wp = Wh + (size_t)wc * KDIM + (((wgr ^ ((wc >> 2) & 1))) << 3);
    const int ww = tid * 16;                            // linear gll dest in wbuf

    // fragment-read offsets
    const int aoff = (wm * 64 + r15) * 40 + hi * 8;     // + rt*640
    int boff[4];
#pragma unroll
    for (int ct = 0; ct < 4; ++ct) {
        int col = wn * 64 + ct * 16 + r15;
        boff[ct] = col * 32 + (((hi >> 1) ^ ((col >> 2) & 1)) << 4) + ((hi & 1) << 3);
    }

    f32x4 acc[4][4];
#pragma unroll
    for (int rt = 0; rt < 4; ++rt)
#pragma unroll
        for (int ct = 0; ct < 4; ++ct)
            acc[rt][ct] = (f32x4){0.f, 0.f, 0.f, 0.f};

    float4 xr[3];

    // ---- prologue: order X0, W0, X1, W1, X2 ----
    {
        float4 x0 = *(const float4*)(Xp + 0);
        gll16(Wp + 0 * 16, smem + WB0 + 0 * WB_STRIDE + ww);
        xr[1] = *(const float4*)(Xp + 1 * 16);
        gll16(Wp + 1 * 16, smem + WB0 + 1 * WB_STRIDE + ww);
        xr[2] = *(const float4*)(Xp + 2 * 16);
        asm volatile("s_waitcnt vmcnt(4)" ::: "memory");   // X0 landed; [W0,X1,W1,X2] in flight
        *(f16x4*)(smem + xw) = cvt4(x0);                   // stage X0 -> xbuf0
    }

#pragma unroll
    for (int kt = 0; kt < 32; ++kt) {
        // (b) counted wait: retires the two oldest = {W(kt), X(kt+1)} under any
        //     intra-step issue order; leaves {W(kt+1), X(kt+2)} in flight.
        if (kt <= 29)      asm volatile("s_waitcnt vmcnt(2)" ::: "memory");
        else if (kt == 30) asm volatile("s_waitcnt vmcnt(1)" ::: "memory");
        else               asm volatile("s_waitcnt vmcnt(0)" ::: "memory");
        asm volatile("s_waitcnt lgkmcnt(0)" ::: "memory"); // my ds_writes committed
        __builtin_amdgcn_s_barrier();
        // (d) W(kt+2) -> ring slot (readers of that slot finished pre-barrier)
        if (kt <= 29)
            gll16(Wp + (size_t)(kt + 2) * 16,
                  smem + WB0 + ((kt + 2) % 3) * WB_STRIDE + ww);
        // (e) stage X(kt+1) (loaded 2 steps ago -> 2 periods of latency slack)
        if (kt <= 30)
            *(f16x4*)(smem + ((kt + 1) & 1) * XB_STRIDE + xw) = cvt4(xr[(kt + 1) % 3]);
        // (a) issue X(kt+3)
        if (kt <= 28)
            xr[kt % 3] = *(const float4*)(Xp + (size_t)(kt + 3) * 16);
        // (f) compute step kt
        {
            const char* xb = smem + (kt & 1) * XB_STRIDE;
            const char* wb = smem + WB0 + (kt % 3) * WB_STRIDE;
            f16x4 bfr[4];
#pragma unroll
            for (int ct = 0; ct < 4; ++ct)
                bfr[ct] = *(const f16x4*)(wb + boff[ct]);
#pragma unroll
            for (int rt = 0; rt < 4; ++rt) {
                f16x4 a = *(const f16x4*)(xb + aoff + rt * 640);
#pragma unroll
                for (int ct = 0; ct < 4; ++ct)
                    acc[rt][ct] = __builtin_amdgcn_mfma_f32_16x16x16f16(a, bfr[ct], acc[rt][ct], 0, 0, 0);
            }
        }
    }

    // ---- epilogue: 2 passes of 64 rows (E overlays dead staging region) ----
    asm volatile("s_waitcnt lgkmcnt(0)" ::: "memory");
    __builtin_amdgcn_s_barrier();

    float bl[4];
#pragma unroll
    for (int ct = 0; ct < 4; ++ct) bl[ct] = biasN[wn * 64 + ct * 16 + r15];

    for (int p = 0; p < 2; ++p) {
        if (wm == p) {
            float* Ef = (float*)smem;
#pragma unroll
            for (int rt = 0; rt < 4; ++rt)
#pragma unroll
                for (int ct = 0; ct < 4; ++ct) {
                    const int col = wn * 64 + ct * 16 + r15;
#pragma unroll
                    for (int reg = 0; reg < 4; ++reg) {
                        const int row = rt * 16 + hi * 4 + reg;
                        float z = acc[rt][ct][reg] + bl[ct];
                        Ef[row * EPI_S + col] = __builtin_amdgcn_rcpf(1.f + __expf(-z));
                    }
                }
        }
        asm volatile("s_waitcnt lgkmcnt(0)" ::: "memory");
        __builtin_amdgcn_s_barrier();
        {   // thread: row = tid>>3 (64 rows), tree-group tg = tid&7 (8 trees each);
            // read rotation j' = (j+tg)&7 -> 2-way (free) E banks instead of 8-way
            const float* Ef = (const float*)smem;
            const float* abl = (const float*)(smem + AB_OFF);
            float* Pf = (float*)(smem + P_OFF);
            const int row = tid >> 3, tg = tid & 7;
            float s0 = 0.f, s1 = 0.f;
#pragma unroll
            for (int j = 0; j < 8; ++j) {
                const int t = tg * 8 + ((j + tg) & 7);
                float4 dv = *(const float4*)&Ef[row * EPI_S + t * 4];
                const float* abt = &abl[t * 10];
                float inv = __builtin_amdgcn_rcpf(4.f + dv.w + 1e-8f);
                s0 += (abt[0] + dv.x * abt[2] + dv.y * abt[4] + dv.z * abt[6] + dv.w * abt[8]) * inv;
                s1 += (abt[1] + dv.x * abt[3] + dv.y * abt[5] + dv.z * abt[7] + dv.w * abt[9]) * inv;
            }
            Pf[row * P_S + tg * 2 + 0] = s0;
            Pf[row * P_S + tg * 2 + 1] = s1;
        }
        asm volatile("s_waitcnt lgkmcnt(0)" ::: "memory");
        __builtin_amdgcn_s_barrier();
        if (tid < 128) {
            const float* Pf = (const float*)(smem + P_OFF);
            const int row = tid >> 1, c = tid & 1;
            float s = 0.f;
#pragma unroll
            for (int g = 0; g < 8; ++g) s += Pf[row * P_S + g * 2 + c];
            out[(size_t)(gr0 + p * 64 + row) * 2 + c] = s;
        }
        if (p == 0) {
            asm volatile("s_waitcnt lgkmcnt(0)" ::: "memory");
            __builtin_amdgcn_s_barrier();
        }
    }
}

extern "C" void kernel_launch(void* const* d_in, const int* in_sizes, int n_in,
                              void* d_out, int out_size, void* d_ws, size_t ws_size,
                              hipStream_t stream) {
    const float* x  = (const float*)d_in[0];
    const float* tp = (const float*)d_in[1];
    const float* tw = (const float*)d_in[2];
    float* out = (float*)d_out;

    _Float16* Wh = (_Float16*)d_ws;
    float* biasN = (float*)((char*)d_ws + 262144);
    float* AB    = (float*)((char*)d_ws + 263168);

    (void)hipFuncSetAttribute((const void*)reinterpret_cast<const void*>(&main_kernel),
                              hipFuncAttributeMaxDynamicSharedMemorySize, LDS_BYTES);

    prep_kernel<<<256, 128, 0, stream>>>(tp, tw, Wh, biasN, AB);
    main_kernel<<<512, 512, LDS_BYTES, stream>>>(x, Wh, biasN, AB, out);
}